// Round 1
// baseline (1419.725 us; speedup 1.0000x reference)
//
#include <hip/hip_runtime.h>

typedef unsigned short u16;
typedef __attribute__((ext_vector_type(8))) short bf16x8;
typedef __attribute__((ext_vector_type(4))) float f32x4;

__device__ __forceinline__ u16 f2b(float f) {
    union { unsigned int i; float f; } x; x.f = f;
    unsigned int r = (x.i + 0x7fffu + ((x.i >> 16) & 1u)) >> 16;
    return (u16)r;
}

__device__ __forceinline__ void gload16(const u16* g, u16* l) {
    __builtin_amdgcn_global_load_lds(
        (const __attribute__((address_space(1))) void*)g,
        (__attribute__((address_space(3))) void*)l, 16, 0, 0);
}

// ---------------- fp32 -> bf16 weight conversion ----------------
__global__ __launch_bounds__(256) void f2b_k(const float* __restrict__ in,
                                             u16* __restrict__ out, int n4) {
    const int i = blockIdx.x * 256 + threadIdx.x;
    if (i < n4) {
        float4 v = ((const float4*)in)[i];
        ushort4 o = { f2b(v.x), f2b(v.y), f2b(v.z), f2b(v.w) };
        ((ushort4*)out)[i] = o;
    }
}

// ---------------- embedding gather ----------------
__global__ __launch_bounds__(256) void embed_k(const int* __restrict__ ids,
                                               const float* __restrict__ E,
                                               float* __restrict__ x) {
    const int n = blockIdx.x, t = threadIdx.x;
    const int id = ids[n];
    float4 e = ((const float4*)(E + (size_t)id * 1024))[t];
    ((float4*)(x + (size_t)n * 1024))[t] = e;
}

// ---------------- static physics: retention/gate/r^128 per (l,h,i,j) ----------------
__global__ __launch_bounds__(256) void physics_k(
        const float* __restrict__ W_LTM, const float* __restrict__ V_T0,
        const float* __restrict__ V_gs, const float* __restrict__ beta_tau,
        const float* __restrict__ beta_gm, const float* __restrict__ C_ch,
        const float* __restrict__ gammaP, const float* __restrict__ alphaP,
        const float* __restrict__ ICthr, float* __restrict__ ret,
        float* __restrict__ gat, float* __restrict__ rp) {
    const int idx = blockIdx.x * 256 + threadIdx.x;   // < L*H*4096
    const int lh = idx >> 12;   // l*H + h
    const int l  = lh >> 4;     // H = 16
    const float W    = W_LTM[idx];
    const float veff = V_gs[lh] - V_T0[lh] + W;
    const float sp   = fmaxf(veff, 0.f) + log1pf(expf(-fabsf(veff)));  // softplus
    const float gch  = beta_tau[lh] * sp;
    const float G    = beta_gm[lh] * sp / (1.f + expf(-veff));
    const float sgn  = tanhf(alphaP[l] * (gch - ICthr[l]));
    const float e1   = gch / C_ch[lh];
    ret[idx] = expf(-e1);            // r = 1 - lam
    rp[idx]  = expf(-128.f * e1);    // r^128 (chunk decay), computed exactly
    gat[idx] = gammaP[lh] * sgn * G;
}

// ---------------- LayerNorm over D=1024, one block per row ----------------
template<bool OUTB>
__global__ __launch_bounds__(256) void ln_rows(const float* __restrict__ X,
                                               const float* __restrict__ g,
                                               const float* __restrict__ bb,
                                               void* __restrict__ OUT) {
    const int n = blockIdx.x, t = threadIdx.x;
    const float4 xv = ((const float4*)(X + (size_t)n * 1024))[t];
    float s  = xv.x + xv.y + xv.z + xv.w;
    float s2 = xv.x * xv.x + xv.y * xv.y + xv.z * xv.z + xv.w * xv.w;
#pragma unroll
    for (int m = 32; m; m >>= 1) { s += __shfl_xor(s, m); s2 += __shfl_xor(s2, m); }
    __shared__ float sh[8];
    if ((t & 63) == 0) { sh[t >> 6] = s; sh[4 + (t >> 6)] = s2; }
    __syncthreads();
    s  = sh[0] + sh[1] + sh[2] + sh[3];
    s2 = sh[4] + sh[5] + sh[6] + sh[7];
    const float mean = s * (1.f / 1024.f);
    const float rstd = rsqrtf(s2 * (1.f / 1024.f) - mean * mean + 1e-5f);
    const int d0 = t * 4;
    const float4 gv = *(const float4*)&g[d0];
    const float4 bv = *(const float4*)&bb[d0];
    float o0 = (xv.x - mean) * rstd * gv.x + bv.x;
    float o1 = (xv.y - mean) * rstd * gv.y + bv.y;
    float o2 = (xv.z - mean) * rstd * gv.z + bv.z;
    float o3 = (xv.w - mean) * rstd * gv.w + bv.w;
    if (OUTB) {
        ushort4 o = { f2b(o0), f2b(o1), f2b(o2), f2b(o3) };
        ((ushort4*)((u16*)OUT + (size_t)n * 1024))[t] = o;
    } else {
        float4 o = { o0, o1, o2, o3 };
        ((float4*)((float*)OUT + (size_t)n * 1024))[t] = o;
    }
}

// ---------------- causal depthwise conv (k=3, left pad 2) + residual, out bf16 ----------------
__global__ __launch_bounds__(256) void conv_k(const float* __restrict__ hln,
                                              const float* __restrict__ w,
                                              const float* __restrict__ cb,
                                              u16* __restrict__ out) {
    const int n = blockIdx.x;
    const int tt = n & 2047;           // T = 2048
    const int d0 = threadIdx.x * 4;
    const float4 c = *(const float4*)&hln[(size_t)n * 1024 + d0];
    float4 m1 = { 0, 0, 0, 0 }, m2 = { 0, 0, 0, 0 };
    if (tt >= 1) m1 = *(const float4*)&hln[(size_t)(n - 1) * 1024 + d0];
    if (tt >= 2) m2 = *(const float4*)&hln[(size_t)(n - 2) * 1024 + d0];
    const float4 w0 = *(const float4*)&w[d0];
    const float4 w1 = *(const float4*)&w[1024 + d0];
    const float4 w2 = *(const float4*)&w[2048 + d0];
    const float4 cv = *(const float4*)&cb[d0];
    float o0 = c.x + m2.x * w0.x + m1.x * w1.x + c.x * w2.x + cv.x;
    float o1 = c.y + m2.y * w0.y + m1.y * w1.y + c.y * w2.y + cv.y;
    float o2 = c.z + m2.z * w0.z + m1.z * w1.z + c.z * w2.z + cv.z;
    float o3 = c.w + m2.w * w0.w + m1.w * w1.w + c.w * w2.w + cv.w;
    ushort4 o = { f2b(o0), f2b(o1), f2b(o2), f2b(o3) };
    *(ushort4*)&out[(size_t)n * 1024 + d0] = o;
}

// ---------------- k head-LN over dk=64, in-place on fp32 qkv ----------------
__global__ __launch_bounds__(256) void kln_k(float* __restrict__ qkv,
                                             const float* __restrict__ g,
                                             const float* __restrict__ bb) {
    const int row = blockIdx.x * 4 + (threadIdx.x >> 6);
    const int lane = threadIdx.x & 63;
    const int n = row >> 4, h = row & 15;        // H = 16
    float* p = qkv + (size_t)n * 3072 + 1024 + h * 64 + lane;
    const float x = *p;
    float s = x, s2 = x * x;
#pragma unroll
    for (int m = 32; m; m >>= 1) { s += __shfl_xor(s, m); s2 += __shfl_xor(s2, m); }
    const float mean = s * (1.f / 64.f);
    const float rstd = rsqrtf(s2 * (1.f / 64.f) - mean * mean + 1e-5f);
    *p = (x - mean) * rstd * g[lane] + bb[lane];
}

// ---------------- bf16 B^T GEMM, m97 recipe ----------------
template<int MODE>
__global__ __launch_bounds__(256, 2) void gemm_bt(const u16* __restrict__ A,
                                                  const u16* __restrict__ Bm,
                                                  float* __restrict__ C,
                                                  int Nn, int K) {
    __shared__ u16 lA[128 * 32];
    __shared__ u16 lB[128 * 32];
    const int t = threadIdx.x;
    const int lane = t & 63, wave = t >> 6;
    const int wm = (wave >> 1) * 64, wn = (wave & 1) * 64;
    const int m0 = blockIdx.y * 128, n0 = blockIdx.x * 128;
    f32x4 acc[4][4] = {};
    const int sr = t >> 2, sc = (t & 3) * 8;
    const u16* Ap = A + (size_t)(m0 + sr) * K + sc;
    const u16* Bp = Bm + (size_t)(n0 + sr) * K + sc;
    u16* lAw = lA + t * 8;
    u16* lBw = lB + t * 8;
    const int fr = lane & 15, fk = (lane >> 4) * 8;
    for (int k0 = 0; k0 < K; k0 += 32) {
        __syncthreads();
        gload16(Ap, lAw);
        gload16(Ap + (size_t)64 * K, lAw + 2048);
        gload16(Bp, lBw);
        gload16(Bp + (size_t)64 * K, lBw + 2048);
        Ap += 32; Bp += 32;
        __syncthreads();
        bf16x8 af[4], bf[4];
#pragma unroll
        for (int i = 0; i < 4; ++i) af[i] = *(const bf16x8*)&lA[(wm + i * 16 + fr) * 32 + fk];
#pragma unroll
        for (int i = 0; i < 4; ++i) bf[i] = *(const bf16x8*)&lB[(wn + i * 16 + fr) * 32 + fk];
#pragma unroll
        for (int i = 0; i < 4; ++i)
#pragma unroll
            for (int j = 0; j < 4; ++j)
                acc[i][j] = __builtin_amdgcn_mfma_f32_16x16x32_bf16(af[i], bf[j], acc[i][j], 0, 0, 0);
    }
    const int col = lane & 15, rw = (lane >> 4) * 4;
#pragma unroll
    for (int i = 0; i < 4; ++i)
#pragma unroll
        for (int j = 0; j < 4; ++j)
#pragma unroll
            for (int r = 0; r < 4; ++r) {
                const int gm = m0 + wm + i * 16 + rw + r;
                const int gn = n0 + wn + j * 16 + col;
                if (MODE == 0) C[(size_t)gm * Nn + gn] = acc[i][j][r];
                else           C[(size_t)gm * Nn + gn] += acc[i][j][r];
            }
}

// ============== chunked linear scan: F_t = r*F_{t-1} + g*(v_t k_t^T) ==============
// 16 chunks of 128 steps.

// Pass A: chunk-local final state (zero init), k/v only.
// One block per (b,h,c): grid = B*H*16 = 1024.  Thread owns (i, 16 j's):
//   i = tid>>2 (0..63), j0 = (tid&3)*16.
// Inner loop hand-unrolled x2 with named A/B prefetch buffers, unconditional
// prefetch (up to 2 rows past the chunk end -- lands inside the workspace).
__global__ __launch_bounds__(256, 4) void scanA_k(const float* __restrict__ qkv,
                                                  const float* __restrict__ ret,
                                                  const float* __restrict__ gat,
                                                  float* __restrict__ Floc) {
    const int bid = blockIdx.x;
    const int c = bid & 15, h = (bid >> 4) & 15, b = bid >> 8;
    const int i = threadIdx.x >> 2;
    const int j0 = (threadIdx.x & 3) * 16;
    const int base = (h * 64 + i) * 64 + j0;
    float r[16], g[16], F[16];
#pragma unroll
    for (int u = 0; u < 16; u += 4) {
        *(float4*)&r[u] = *(const float4*)&ret[base + u];
        *(float4*)&g[u] = *(const float4*)&gat[base + u];
    }
#pragma unroll
    for (int u = 0; u < 16; ++u) F[u] = 0.f;

    const size_t row0 = ((size_t)b * 2048 + (size_t)c * 128) * 3072;
    const float* bk = qkv + row0 + 1024 + h * 64 + j0;
    const float* bv = qkv + row0 + 2048 + h * 64 + i;

    float kA[16], kB[16], vA, vB;
#pragma unroll
    for (int u = 0; u < 16; u += 4) *(float4*)&kA[u] = *(const float4*)(bk + u);
    vA = *bv;

    unsigned offB = 3072, offA = 6144;
    for (int t = 0; t < 128; t += 2) {
        // prefetch t+1 -> B
#pragma unroll
        for (int u = 0; u < 16; u += 4) *(float4*)&kB[u] = *(const float4*)(bk + offB + u);
        vB = *(bv + offB);
        offB += 6144;
        // compute t (A)
#pragma unroll
        for (int u = 0; u < 16; ++u) F[u] = r[u] * F[u] + (g[u] * kA[u]) * vA;
        // prefetch t+2 -> A
#pragma unroll
        for (int u = 0; u < 16; u += 4) *(float4*)&kA[u] = *(const float4*)(bk + offA + u);
        vA = *(bv + offA);
        offA += 6144;
        // compute t+1 (B)
#pragma unroll
        for (int u = 0; u < 16; ++u) F[u] = r[u] * F[u] + (g[u] * kB[u]) * vB;
    }
    float* Fo = Floc + ((size_t)((b * 16 + h) * 16 + c)) * 4096 + i * 64 + j0;
#pragma unroll
    for (int u = 0; u < 16; u += 4) *(float4*)&Fo[u] = *(const float4*)&F[u];
}

// Pass B: prefix across chunks. Fin[c] = state entering chunk c.
__global__ __launch_bounds__(256) void scanB_k(const float* __restrict__ rp,
                                               const float* __restrict__ Floc,
                                               float* __restrict__ Fin) {
    const int idx = blockIdx.x * 256 + threadIdx.x;   // < B*H*4096 = 262144
    const int e = idx & 4095;
    const int bh = idx >> 12;
    const int h = bh & 15;
    const float rpv = rp[h * 4096 + e];
    float F = 0.f;
#pragma unroll
    for (int c = 0; c < 16; ++c) {
        const size_t o = ((size_t)bh * 16 + c) * 4096 + e;
        Fin[o] = F;
        F = rpv * F + Floc[o];
    }
}

// Pass C: outputs, seeded with Fin.
// Two blocks per (b,h,c) (ig = half of i-range): grid = B*H*16*2 = 2048.
// Thread owns (i, 8 j's): il = tid>>3 (0..31), jq = tid&7, i = ig*32+il.
// 3-deep shfl reduction over jq; unroll x2 with A/B prefetch buffers.
__global__ __launch_bounds__(256, 4) void scanC_k(const float* __restrict__ qkv,
                                                  const float* __restrict__ ret,
                                                  const float* __restrict__ gat,
                                                  const float* __restrict__ Wl,
                                                  const float* __restrict__ Fin,
                                                  u16* __restrict__ y) {
    const int bid = blockIdx.x;
    const int ig = bid & 1, c = (bid >> 1) & 15, h = (bid >> 5) & 15, b = bid >> 9;
    const int il = threadIdx.x >> 3;
    const int jq = threadIdx.x & 7;
    const int i = ig * 32 + il, j0 = jq * 8;
    const int base = (h * 64 + i) * 64 + j0;
    float r[8], g[8], w[8], F[8];
    const float* Fi = Fin + ((size_t)((b * 16 + h) * 16 + c)) * 4096 + i * 64 + j0;
#pragma unroll
    for (int u = 0; u < 8; u += 4) {
        *(float4*)&r[u] = *(const float4*)&ret[base + u];
        *(float4*)&g[u] = *(const float4*)&gat[base + u];
        *(float4*)&w[u] = *(const float4*)&Wl[base + u];
        *(float4*)&F[u] = *(const float4*)(Fi + u);
    }
    const size_t row0 = ((size_t)b * 2048 + (size_t)c * 128) * 3072;
    const float* bq = qkv + row0 + h * 64 + j0;
    const float* bk = bq + 1024;
    const float* bv = qkv + row0 + 2048 + h * 64 + i;
    u16* py = y + ((size_t)b * 2048 + (size_t)c * 128) * 1024 + h * 64 + i;

    float qA[8], qB[8], kA[8], kB[8], vA, vB;
#pragma unroll
    for (int u = 0; u < 8; u += 4) {
        *(float4*)&qA[u] = *(const float4*)(bq + u);
        *(float4*)&kA[u] = *(const float4*)(bk + u);
    }
    vA = *bv;

    unsigned offB = 3072, offA = 6144;
    for (int t = 0; t < 128; t += 2) {
        // prefetch t+1 -> B
#pragma unroll
        for (int u = 0; u < 8; u += 4) {
            *(float4*)&qB[u] = *(const float4*)(bq + offB + u);
            *(float4*)&kB[u] = *(const float4*)(bk + offB + u);
        }
        vB = *(bv + offB);
        offB += 6144;
        // compute t (A)
        {
#pragma unroll
            for (int u = 0; u < 8; ++u) F[u] = r[u] * F[u] + (g[u] * kA[u]) * vA;
            float p0 = (w[0] + F[0]) * qA[0];
            float p1 = (w[1] + F[1]) * qA[1];
            p0 += (w[2] + F[2]) * qA[2];
            p1 += (w[3] + F[3]) * qA[3];
            p0 += (w[4] + F[4]) * qA[4];
            p1 += (w[5] + F[5]) * qA[5];
            p0 += (w[6] + F[6]) * qA[6];
            p1 += (w[7] + F[7]) * qA[7];
            float p = p0 + p1;
            p += __shfl_xor(p, 1);
            p += __shfl_xor(p, 2);
            p += __shfl_xor(p, 4);
            if (jq == 0) py[0] = f2b(p);
        }
        // prefetch t+2 -> A
#pragma unroll
        for (int u = 0; u < 8; u += 4) {
            *(float4*)&qA[u] = *(const float4*)(bq + offA + u);
            *(float4*)&kA[u] = *(const float4*)(bk + offA + u);
        }
        vA = *(bv + offA);
        offA += 6144;
        // compute t+1 (B)
        {
#pragma unroll
            for (int u = 0; u < 8; ++u) F[u] = r[u] * F[u] + (g[u] * kB[u]) * vB;
            float p0 = (w[0] + F[0]) * qB[0];
            float p1 = (w[1] + F[1]) * qB[1];
            p0 += (w[2] + F[2]) * qB[2];
            p1 += (w[3] + F[3]) * qB[3];
            p0 += (w[4] + F[4]) * qB[4];
            p1 += (w[5] + F[5]) * qB[5];
            p0 += (w[6] + F[6]) * qB[6];
            p1 += (w[7] + F[7]) * qB[7];
            float p = p0 + p1;
            p += __shfl_xor(p, 1);
            p += __shfl_xor(p, 2);
            p += __shfl_xor(p, 4);
            if (jq == 0) py[1024] = f2b(p);
        }
        py += 2048;
    }
}

extern "C" void kernel_launch(void* const* d_in, const int* in_sizes, int n_in,
                              void* d_out, int out_size, void* d_ws, size_t ws_size,
                              hipStream_t stream) {
    constexpr int Bz = 4, T = 2048, Dd = 1024, Hh = 16, Vv = 8192, Ll = 2;
    constexpr int Nn = Bz * T;   // 8192 tokens
    const int*   ids      = (const int*)d_in[0];
    const float* embed_W  = (const float*)d_in[2];
    const float* conv_w   = (const float*)d_in[3];
    const float* conv_b   = (const float*)d_in[4];
    const float* Wqkv     = (const float*)d_in[5];
    const float* Wo       = (const float*)d_in[6];
    const float* W_LTM    = (const float*)d_in[7];
    const float* V_T0     = (const float*)d_in[8];
    const float* V_gs     = (const float*)d_in[9];
    const float* beta_tau = (const float*)d_in[10];
    const float* beta_gm  = (const float*)d_in[11];
    const float* C_ch     = (const float*)d_in[12];
    const float* gammaP   = (const float*)d_in[13];
    const float* alphaP   = (const float*)d_in[14];
    const float* ICthr    = (const float*)d_in[15];
    const float* ln1_g    = (const float*)d_in[16];
    const float* ln1_b    = (const float*)d_in[17];
    const float* lnk_g    = (const float*)d_in[18];
    const float* lnk_b    = (const float*)d_in[19];
    const float* lnf_g    = (const float*)d_in[20];
    const float* lnf_b    = (const float*)d_in[21];
    const float* head_W   = (const float*)d_in[22];

    // workspace carve (~220 MB)
    float* x    = (float*)d_ws;                                  // fp32 N*D
    float* qkvF = x + (size_t)Nn * Dd;                           // fp32 N*3D
    float* ret  = qkvF + (size_t)Nn * 3 * Dd;                    // fp32 L*H*4096
    float* gat  = ret + (size_t)Ll * Hh * 4096;
    float* rp   = gat + (size_t)Ll * Hh * 4096;                  // fp32 L*H*4096 (r^128)
    float* hln  = rp + (size_t)Ll * Hh * 4096;                   // fp32 N*D
    u16*  yb    = (u16*)hln;                                     // bf16 N*D  (aliases hln 1st half)
    u16*  xf    = yb + (size_t)Nn * Dd;                          // bf16 N*D  (aliases hln 2nd half)
    float* Fin  = (float*)xf;                                    // fp32 B*H*16*4096 = same bytes as xf
    u16*  hb    = (u16*)(hln + (size_t)Nn * Dd);                 // bf16 N*D
    float* Floc = (float*)hb;                                    // fp32 B*H*16*4096 = same bytes as hb
    u16*  wq_b  = hb + (size_t)Nn * Dd;                          // bf16 L*3D*D
    u16*  wo_b  = wq_b + (size_t)Ll * 3 * Dd * Dd;               // bf16 L*D*D
    u16*  wh_b  = wo_b + (size_t)Ll * Dd * Dd;                   // bf16 V*D

    // weight conversions
    f2b_k<<<(Ll * 3 * Dd * Dd / 4 + 255) / 256, 256, 0, stream>>>(Wqkv, wq_b, Ll * 3 * Dd * Dd / 4);
    f2b_k<<<(Ll * Dd * Dd / 4 + 255) / 256, 256, 0, stream>>>(Wo, wo_b, Ll * Dd * Dd / 4);
    f2b_k<<<(Vv * Dd / 4 + 255) / 256, 256, 0, stream>>>(head_W, wh_b, Vv * Dd / 4);

    embed_k<<<Nn, 256, 0, stream>>>(ids, embed_W, x);
    physics_k<<<(Ll * Hh * 4096) / 256, 256, 0, stream>>>(W_LTM, V_T0, V_gs, beta_tau,
                                                          beta_gm, C_ch, gammaP, alphaP,
                                                          ICthr, ret, gat, rp);
    for (int l = 0; l < Ll; ++l) {
        const float* retl = ret + (size_t)l * Hh * 4096;
        const float* gatl = gat + (size_t)l * Hh * 4096;
        ln_rows<false><<<Nn, 256, 0, stream>>>(x, ln1_g + l * Dd, ln1_b + l * Dd, hln);
        conv_k<<<Nn, 256, 0, stream>>>(hln, conv_w + l * 3 * Dd, conv_b + l * Dd, hb);
        gemm_bt<0><<<dim3(3 * Dd / 128, Nn / 128), 256, 0, stream>>>(
            hb, wq_b + (size_t)l * 3 * Dd * Dd, qkvF, 3 * Dd, Dd);
        kln_k<<<Nn * Hh / 4, 256, 0, stream>>>(qkvF, lnk_g + l * 64, lnk_b + l * 64);
        scanA_k<<<Bz * Hh * 16, 256, 0, stream>>>(qkvF, retl, gatl, Floc);
        scanB_k<<<Bz * Hh * 4096 / 256, 256, 0, stream>>>(rp + (size_t)l * Hh * 4096, Floc, Fin);
        scanC_k<<<Bz * Hh * 16 * 2, 256, 0, stream>>>(qkvF, retl, gatl,
                                                      W_LTM + (size_t)l * Hh * 4096, Fin, yb);
        gemm_bt<1><<<dim3(Dd / 128, Nn / 128), 256, 0, stream>>>(
            yb, wo_b + (size_t)l * Dd * Dd, x, Dd, Dd);
    }
    ln_rows<true><<<Nn, 256, 0, stream>>>(x, lnf_g, lnf_b, xf);
    gemm_bt<0><<<dim3(Vv / 128, Nn / 128), 256, 0, stream>>>(xf, wh_b, (float*)d_out, Vv, Dd);
}

// Round 3
// 1417.917 us; speedup vs baseline: 1.0013x; 1.0013x over previous
//
#include <hip/hip_runtime.h>

typedef unsigned short u16;
typedef __attribute__((ext_vector_type(8))) short bf16x8;
typedef __attribute__((ext_vector_type(4))) float f32x4;

__device__ __forceinline__ u16 f2b(float f) {
    union { unsigned int i; float f; } x; x.f = f;
    unsigned int r = (x.i + 0x7fffu + ((x.i >> 16) & 1u)) >> 16;
    return (u16)r;
}

__device__ __forceinline__ void gload16(const u16* g, u16* l) {
    __builtin_amdgcn_global_load_lds(
        (const __attribute__((address_space(1))) void*)g,
        (__attribute__((address_space(3))) void*)l, 16, 0, 0);
}

// ---------------- fp32 -> bf16 weight conversion ----------------
__global__ __launch_bounds__(256) void f2b_k(const float* __restrict__ in,
                                             u16* __restrict__ out, int n4) {
    const int i = blockIdx.x * 256 + threadIdx.x;
    if (i < n4) {
        float4 v = ((const float4*)in)[i];
        ushort4 o = { f2b(v.x), f2b(v.y), f2b(v.z), f2b(v.w) };
        ((ushort4*)out)[i] = o;
    }
}

// ---------------- embedding gather ----------------
__global__ __launch_bounds__(256) void embed_k(const int* __restrict__ ids,
                                               const float* __restrict__ E,
                                               float* __restrict__ x) {
    const int n = blockIdx.x, t = threadIdx.x;
    const int id = ids[n];
    float4 e = ((const float4*)(E + (size_t)id * 1024))[t];
    ((float4*)(x + (size_t)n * 1024))[t] = e;
}

// ---------------- static physics ----------------
__global__ __launch_bounds__(256) void physics_k(
        const float* __restrict__ W_LTM, const float* __restrict__ V_T0,
        const float* __restrict__ V_gs, const float* __restrict__ beta_tau,
        const float* __restrict__ beta_gm, const float* __restrict__ C_ch,
        const float* __restrict__ gammaP, const float* __restrict__ alphaP,
        const float* __restrict__ ICthr, float* __restrict__ ret,
        float* __restrict__ gat, float* __restrict__ rp) {
    const int idx = blockIdx.x * 256 + threadIdx.x;   // < L*H*4096
    const int lh = idx >> 12;   // l*H + h
    const int l  = lh >> 4;     // H = 16
    const float W    = W_LTM[idx];
    const float veff = V_gs[lh] - V_T0[lh] + W;
    const float sp   = fmaxf(veff, 0.f) + log1pf(expf(-fabsf(veff)));  // softplus
    const float gch  = beta_tau[lh] * sp;
    const float G    = beta_gm[lh] * sp / (1.f + expf(-veff));
    const float sgn  = tanhf(alphaP[l] * (gch - ICthr[l]));
    const float e1   = gch / C_ch[lh];
    ret[idx] = expf(-e1);            // r = 1 - lam
    rp[idx]  = expf(-128.f * e1);    // r^128 (chunk decay)
    gat[idx] = gammaP[lh] * sgn * G;
}

// ---------------- LayerNorm over D=1024, one block per row ----------------
template<bool OUTB>
__global__ __launch_bounds__(256) void ln_rows(const float* __restrict__ X,
                                               const float* __restrict__ g,
                                               const float* __restrict__ bb,
                                               void* __restrict__ OUT) {
    const int n = blockIdx.x, t = threadIdx.x;
    const float4 xv = ((const float4*)(X + (size_t)n * 1024))[t];
    float s  = xv.x + xv.y + xv.z + xv.w;
    float s2 = xv.x * xv.x + xv.y * xv.y + xv.z * xv.z + xv.w * xv.w;
#pragma unroll
    for (int m = 32; m; m >>= 1) { s += __shfl_xor(s, m); s2 += __shfl_xor(s2, m); }
    __shared__ float sh[8];
    if ((t & 63) == 0) { sh[t >> 6] = s; sh[4 + (t >> 6)] = s2; }
    __syncthreads();
    s  = sh[0] + sh[1] + sh[2] + sh[3];
    s2 = sh[4] + sh[5] + sh[6] + sh[7];
    const float mean = s * (1.f / 1024.f);
    const float rstd = rsqrtf(s2 * (1.f / 1024.f) - mean * mean + 1e-5f);
    const int d0 = t * 4;
    const float4 gv = *(const float4*)&g[d0];
    const float4 bv = *(const float4*)&bb[d0];
    float o0 = (xv.x - mean) * rstd * gv.x + bv.x;
    float o1 = (xv.y - mean) * rstd * gv.y + bv.y;
    float o2 = (xv.z - mean) * rstd * gv.z + bv.z;
    float o3 = (xv.w - mean) * rstd * gv.w + bv.w;
    if (OUTB) {
        ushort4 o = { f2b(o0), f2b(o1), f2b(o2), f2b(o3) };
        ((ushort4*)((u16*)OUT + (size_t)n * 1024))[t] = o;
    } else {
        float4 o = { o0, o1, o2, o3 };
        ((float4*)((float*)OUT + (size_t)n * 1024))[t] = o;
    }
}

// ---------------- causal depthwise conv (k=3, left pad 2) + residual ----------------
__global__ __launch_bounds__(256) void conv_k(const float* __restrict__ hln,
                                              const float* __restrict__ w,
                                              const float* __restrict__ cb,
                                              u16* __restrict__ out) {
    const int n = blockIdx.x;
    const int tt = n & 2047;           // T = 2048
    const int d0 = threadIdx.x * 4;
    const float4 c = *(const float4*)&hln[(size_t)n * 1024 + d0];
    float4 m1 = { 0, 0, 0, 0 }, m2 = { 0, 0, 0, 0 };
    if (tt >= 1) m1 = *(const float4*)&hln[(size_t)(n - 1) * 1024 + d0];
    if (tt >= 2) m2 = *(const float4*)&hln[(size_t)(n - 2) * 1024 + d0];
    const float4 w0 = *(const float4*)&w[d0];
    const float4 w1 = *(const float4*)&w[1024 + d0];
    const float4 w2 = *(const float4*)&w[2048 + d0];
    const float4 cv = *(const float4*)&cb[d0];
    float o0 = c.x + m2.x * w0.x + m1.x * w1.x + c.x * w2.x + cv.x;
    float o1 = c.y + m2.y * w0.y + m1.y * w1.y + c.y * w2.y + cv.y;
    float o2 = c.z + m2.z * w0.z + m1.z * w1.z + c.z * w2.z + cv.z;
    float o3 = c.w + m2.w * w0.w + m1.w * w1.w + c.w * w2.w + cv.w;
    ushort4 o = { f2b(o0), f2b(o1), f2b(o2), f2b(o3) };
    *(ushort4*)&out[(size_t)n * 1024 + d0] = o;
}

// ---------------- k head-LN over dk=64, in-place on fp32 qkv ----------------
__global__ __launch_bounds__(256) void kln_k(float* __restrict__ qkv,
                                             const float* __restrict__ g,
                                             const float* __restrict__ bb) {
    const int row = blockIdx.x * 4 + (threadIdx.x >> 6);
    const int lane = threadIdx.x & 63;
    const int n = row >> 4, h = row & 15;        // H = 16
    float* p = qkv + (size_t)n * 3072 + 1024 + h * 64 + lane;
    const float x = *p;
    float s = x, s2 = x * x;
#pragma unroll
    for (int m = 32; m; m >>= 1) { s += __shfl_xor(s, m); s2 += __shfl_xor(s2, m); }
    const float mean = s * (1.f / 64.f);
    const float rstd = rsqrtf(s2 * (1.f / 64.f) - mean * mean + 1e-5f);
    *p = (x - mean) * rstd * g[lane] + bb[lane];
}

// ---------------- bf16 B^T GEMM, m97 recipe (kept for Wo: N=1024) ----------------
template<int MODE>
__global__ __launch_bounds__(256, 2) void gemm_bt(const u16* __restrict__ A,
                                                  const u16* __restrict__ Bm,
                                                  float* __restrict__ C,
                                                  int Nn, int K) {
    __shared__ u16 lA[128 * 32];
    __shared__ u16 lB[128 * 32];
    const int t = threadIdx.x;
    const int lane = t & 63, wave = t >> 6;
    const int wm = (wave >> 1) * 64, wn = (wave & 1) * 64;
    const int m0 = blockIdx.y * 128, n0 = blockIdx.x * 128;
    f32x4 acc[4][4] = {};
    const int sr = t >> 2, sc = (t & 3) * 8;
    const u16* Ap = A + (size_t)(m0 + sr) * K + sc;
    const u16* Bp = Bm + (size_t)(n0 + sr) * K + sc;
    u16* lAw = lA + t * 8;
    u16* lBw = lB + t * 8;
    const int fr = lane & 15, fk = (lane >> 4) * 8;
    for (int k0 = 0; k0 < K; k0 += 32) {
        __syncthreads();
        gload16(Ap, lAw);
        gload16(Ap + (size_t)64 * K, lAw + 2048);
        gload16(Bp, lBw);
        gload16(Bp + (size_t)64 * K, lBw + 2048);
        Ap += 32; Bp += 32;
        __syncthreads();
        bf16x8 af[4], bf[4];
#pragma unroll
        for (int i = 0; i < 4; ++i) af[i] = *(const bf16x8*)&lA[(wm + i * 16 + fr) * 32 + fk];
#pragma unroll
        for (int i = 0; i < 4; ++i) bf[i] = *(const bf16x8*)&lB[(wn + i * 16 + fr) * 32 + fk];
#pragma unroll
        for (int i = 0; i < 4; ++i)
#pragma unroll
            for (int j = 0; j < 4; ++j)
                acc[i][j] = __builtin_amdgcn_mfma_f32_16x16x32_bf16(af[i], bf[j], acc[i][j], 0, 0, 0);
    }
    const int col = lane & 15, rw = (lane >> 4) * 4;
#pragma unroll
    for (int i = 0; i < 4; ++i)
#pragma unroll
        for (int j = 0; j < 4; ++j)
#pragma unroll
            for (int r = 0; r < 4; ++r) {
                const int gm = m0 + wm + i * 16 + rw + r;
                const int gn = n0 + wn + j * 16 + col;
                if (MODE == 0) C[(size_t)gm * Nn + gn] = acc[i][j][r];
                else           C[(size_t)gm * Nn + gn] += acc[i][j][r];
            }
}

// ============ 256x256 8-phase bf16 B^T GEMM (T1+T2+T3+T4+T5) ============
// 512 thr = 8 waves (2M x 4N); BK=64 split in two K-halves; LDS 128 KB dbuf.
// Per tile: 4 phases; each stages one half-tile of t+1 (2 x gload_lds).
// Counted s_waitcnt vmcnt(4) at ph2/ph4 (never 0 in steady state):
//   ph2 retires tile t's K1 halves (read at ph3); ph4 retires t+1's K0
//   halves (read at t+1 ph1). Raw s_barrier only -- no __syncthreads.
// T2: LDS write-linear (gload_lds), swizzle folded into SOURCE addr
//   (c = (tid&3)^((tid>>3)&3)) and applied again on the frag read.
template<int MODE>
__global__ __launch_bounds__(512, 2) void gemm256(const u16* __restrict__ A,
                                                  const u16* __restrict__ Bm,
                                                  float* __restrict__ C,
                                                  int Nn, int K, int ntiles) {
    __shared__ u16 lds[65536];   // [buf:2][A/B][kh:2][8192 u16]
    const int tid = threadIdx.x;
    const int lane = tid & 63, wave = tid >> 6;
    const int wm = wave >> 2, wn = wave & 3;
    // T1: XCD-aware swizzle (grid % 8 == 0 for all call sites)
    const int nwg = gridDim.x;
    const int cpx = nwg >> 3;
    const int bid0 = blockIdx.x;
    const int bid = (bid0 & 7) * cpx + (bid0 >> 3);
    const int m0 = (bid / ntiles) * 256, n0 = (bid % ntiles) * 256;

    // staging source (per thread); inverse-swizzled column
    const int sr = tid >> 2;                       // 0..127
    const int sc = (tid & 3) ^ ((tid >> 3) & 3);
    const u16* gA = A + (size_t)(m0 + sr) * K + sc * 8;
    const u16* gB = Bm + (size_t)(n0 + sr) * K + sc * 8;
    const size_t qstep = (size_t)128 * K;
    const int ldst = tid * 8;                      // staging dest (u16), +4096 for rows 128..255

    // frag read offsets (u16): chunk = row*4 + (g ^ ((row>>1)&3)), addr = chunk*8
    const int laneRow = lane & 15, g4 = lane >> 4;
    const int swz = g4 ^ ((laneRow >> 1) & 3);
    const int pA = ((wm * 128 + laneRow) * 4 + swz) * 8;   // + f*512
    const int pB = ((wn * 64 + laneRow) * 4 + swz) * 8;    // + nf*512

    f32x4 acc[8][4] = {};
    const int NT = K >> 6;

    // ---- prologue: stage tile 0 (A-K0, B-K0, A-K1, B-K1) ----
    {
        u16* d = (u16*)lds;
        gload16(gA,              d + ldst);
        gload16(gA + qstep,      d + 4096 + ldst);
        gload16(gB,              d + 16384 + ldst);
        gload16(gB + qstep,      d + 16384 + 4096 + ldst);
        gload16(gA + 32,         d + 8192 + ldst);
        gload16(gA + 32 + qstep, d + 8192 + 4096 + ldst);
        gload16(gB + 32,         d + 24576 + ldst);
        gload16(gB + 32 + qstep, d + 24576 + 4096 + ldst);
    }
    asm volatile("s_waitcnt vmcnt(4)" ::: "memory");
    __builtin_amdgcn_s_barrier();

    for (int t = 0; t < NT; ++t) {
        const u16* lb = lds + (t & 1) * 32768;
        u16* sb = (u16*)lds + ((t + 1) & 1) * 32768;
        const bool st = (t + 1 < NT);
        const int ko = (t + 1) * 64;
        bf16x8 a[8], b0, b1, b2, b3;

        // ---------- phase 1: A-K0 frags + B-K0 lo; stage A-K0 of t+1 ----------
#pragma unroll
        for (int f = 0; f < 8; ++f) a[f] = *(const bf16x8*)(lb + pA + f * 512);
        b0 = *(const bf16x8*)(lb + 16384 + pB);
        b1 = *(const bf16x8*)(lb + 16384 + pB + 512);
        if (st) { gload16(gA + ko, sb + ldst); gload16(gA + ko + qstep, sb + 4096 + ldst); }
        __builtin_amdgcn_s_barrier();
        asm volatile("s_waitcnt lgkmcnt(0)" ::: "memory");
        __builtin_amdgcn_sched_barrier(0);
        __builtin_amdgcn_s_setprio(1);
#pragma unroll
        for (int m = 0; m < 8; ++m) {
            acc[m][0] = __builtin_amdgcn_mfma_f32_16x16x32_bf16(a[m], b0, acc[m][0], 0, 0, 0);
            acc[m][1] = __builtin_amdgcn_mfma_f32_16x16x32_bf16(a[m], b1, acc[m][1], 0, 0, 0);
        }
        __builtin_amdgcn_s_setprio(0);
        __builtin_amdgcn_s_barrier();

        // ---------- phase 2: B-K0 hi; stage B-K0 of t+1; vmcnt(4) ----------
        b2 = *(const bf16x8*)(lb + 16384 + pB + 1024);
        b3 = *(const bf16x8*)(lb + 16384 + pB + 1536);
        if (st) { gload16(gB + ko, sb + 16384 + ldst); gload16(gB + ko + qstep, sb + 16384 + 4096 + ldst); }
        if (st) asm volatile("s_waitcnt vmcnt(4)" ::: "memory");
        else    asm volatile("s_waitcnt vmcnt(0)" ::: "memory");
        __builtin_amdgcn_s_barrier();
        asm volatile("s_waitcnt lgkmcnt(0)" ::: "memory");
        __builtin_amdgcn_sched_barrier(0);
        __builtin_amdgcn_s_setprio(1);
#pragma unroll
        for (int m = 0; m < 8; ++m) {
            acc[m][2] = __builtin_amdgcn_mfma_f32_16x16x32_bf16(a[m], b2, acc[m][2], 0, 0, 0);
            acc[m][3] = __builtin_amdgcn_mfma_f32_16x16x32_bf16(a[m], b3, acc[m][3], 0, 0, 0);
        }
        __builtin_amdgcn_s_setprio(0);
        __builtin_amdgcn_s_barrier();

        // ---------- phase 3: A-K1 frags + B-K1 lo; stage A-K1 of t+1 ----------
#pragma unroll
        for (int f = 0; f < 8; ++f) a[f] = *(const bf16x8*)(lb + 8192 + pA + f * 512);
        b0 = *(const bf16x8*)(lb + 24576 + pB);
        b1 = *(const bf16x8*)(lb + 24576 + pB + 512);
        if (st) { gload16(gA + ko + 32, sb + 8192 + ldst); gload16(gA + ko + 32 + qstep, sb + 8192 + 4096 + ldst); }
        __builtin_amdgcn_s_barrier();
        asm volatile("s_waitcnt lgkmcnt(0)" ::: "memory");
        __builtin_amdgcn_sched_barrier(0);
        __builtin_amdgcn_s_setprio(1);
#pragma unroll
        for (int m = 0; m < 8; ++m) {
            acc[m][0] = __builtin_amdgcn_mfma_f32_16x16x32_bf16(a[m], b0, acc[m][0], 0, 0, 0);
            acc[m][1] = __builtin_amdgcn_mfma_f32_16x16x32_bf16(a[m], b1, acc[m][1], 0, 0, 0);
        }
        __builtin_amdgcn_s_setprio(0);
        __builtin_amdgcn_s_barrier();

        // ---------- phase 4: B-K1 hi; stage B-K1 of t+1; vmcnt(4) ----------
        b2 = *(const bf16x8*)(lb + 24576 + pB + 1024);
        b3 = *(const bf16x8*)(lb + 24576 + pB + 1536);
        if (st) { gload16(gB + ko + 32, sb + 24576 + ldst); gload16(gB + ko + 32 + qstep, sb + 24576 + 4096 + ldst); }
        if (st) asm volatile("s_waitcnt vmcnt(4)" ::: "memory");
        else    asm volatile("s_waitcnt vmcnt(0)" ::: "memory");
        __builtin_amdgcn_s_barrier();
        asm volatile("s_waitcnt lgkmcnt(0)" ::: "memory");
        __builtin_amdgcn_sched_barrier(0);
        __builtin_amdgcn_s_setprio(1);
#pragma unroll
        for (int m = 0; m < 8; ++m) {
            acc[m][2] = __builtin_amdgcn_mfma_f32_16x16x32_bf16(a[m], b2, acc[m][2], 0, 0, 0);
            acc[m][3] = __builtin_amdgcn_mfma_f32_16x16x32_bf16(a[m], b3, acc[m][3], 0, 0, 0);
        }
        __builtin_amdgcn_s_setprio(0);
        __builtin_amdgcn_s_barrier();
    }

    // ---- epilogue: C write ----
    const int col = lane & 15, rw4 = (lane >> 4) * 4;
    const int gm0 = m0 + wm * 128, gn0 = n0 + wn * 64;
#pragma unroll
    for (int m = 0; m < 8; ++m)
#pragma unroll
        for (int n = 0; n < 4; ++n) {
            float* cp = C + (size_t)(gm0 + m * 16 + rw4) * Nn + gn0 + n * 16 + col;
#pragma unroll
            for (int r = 0; r < 4; ++r) {
                if (MODE == 0) cp[(size_t)r * Nn] = acc[m][n][r];
                else           cp[(size_t)r * Nn] += acc[m][n][r];
            }
        }
}

// ============== chunked linear scan: F_t = r*F_{t-1} + g*(v_t k_t^T) ==============
// 16 chunks of 128 steps.

// Pass A: chunk-local final state (zero init), k/v only.
__global__ __launch_bounds__(256, 4) void scanA_k(const float* __restrict__ qkv,
                                                  const float* __restrict__ ret,
                                                  const float* __restrict__ gat,
                                                  float* __restrict__ Floc) {
    const int bid = blockIdx.x;
    const int c = bid & 15, h = (bid >> 4) & 15, b = bid >> 8;
    const int i = threadIdx.x >> 2;
    const int j0 = (threadIdx.x & 3) * 16;
    const int base = (h * 64 + i) * 64 + j0;
    float r[16], g[16], F[16];
#pragma unroll
    for (int u = 0; u < 16; u += 4) {
        *(float4*)&r[u] = *(const float4*)&ret[base + u];
        *(float4*)&g[u] = *(const float4*)&gat[base + u];
    }
#pragma unroll
    for (int u = 0; u < 16; ++u) F[u] = 0.f;

    const size_t row0 = ((size_t)b * 2048 + (size_t)c * 128) * 3072;
    const float* bk = qkv + row0 + 1024 + h * 64 + j0;
    const float* bv = qkv + row0 + 2048 + h * 64 + i;

    float kA[16], kB[16], vA, vB;
#pragma unroll
    for (int u = 0; u < 16; u += 4) *(float4*)&kA[u] = *(const float4*)(bk + u);
    vA = *bv;

    unsigned offB = 3072, offA = 6144;
    for (int t = 0; t < 128; t += 2) {
#pragma unroll
        for (int u = 0; u < 16; u += 4) *(float4*)&kB[u] = *(const float4*)(bk + offB + u);
        vB = *(bv + offB);
        offB += 6144;
#pragma unroll
        for (int u = 0; u < 16; ++u) F[u] = r[u] * F[u] + (g[u] * kA[u]) * vA;
#pragma unroll
        for (int u = 0; u < 16; u += 4) *(float4*)&kA[u] = *(const float4*)(bk + offA + u);
        vA = *(bv + offA);
        offA += 6144;
#pragma unroll
        for (int u = 0; u < 16; ++u) F[u] = r[u] * F[u] + (g[u] * kB[u]) * vB;
    }
    float* Fo = Floc + ((size_t)((b * 16 + h) * 16 + c)) * 4096 + i * 64 + j0;
#pragma unroll
    for (int u = 0; u < 16; u += 4) *(float4*)&Fo[u] = *(const float4*)&F[u];
}

// Pass B: prefix across chunks.
__global__ __launch_bounds__(256) void scanB_k(const float* __restrict__ rp,
                                               const float* __restrict__ Floc,
                                               float* __restrict__ Fin) {
    const int idx = blockIdx.x * 256 + threadIdx.x;   // < B*H*4096
    const int e = idx & 4095;
    const int bh = idx >> 12;
    const int h = bh & 15;
    const float rpv = rp[h * 4096 + e];
    float F = 0.f;
#pragma unroll
    for (int c = 0; c < 16; ++c) {
        const size_t o = ((size_t)bh * 16 + c) * 4096 + e;
        Fin[o] = F;
        F = rpv * F + Floc[o];
    }
}

// Pass C: outputs, seeded with Fin.
__global__ __launch_bounds__(256, 4) void scanC_k(const float* __restrict__ qkv,
                                                  const float* __restrict__ ret,
                                                  const float* __restrict__ gat,
                                                  const float* __restrict__ Wl,
                                                  const float* __restrict__ Fin,
                                                  u16* __restrict__ y) {
    const int bid = blockIdx.x;
    const int ig = bid & 1, c = (bid >> 1) & 15, h = (bid >> 5) & 15, b = bid >> 9;
    const int il = threadIdx.x >> 3;
    const int jq = threadIdx.x & 7;
    const int i = ig * 32 + il, j0 = jq * 8;
    const int base = (h * 64 + i) * 64 + j0;
    float r[8], g[8], w[8], F[8];
    const float* Fi = Fin + ((size_t)((b * 16 + h) * 16 + c)) * 4096 + i * 64 + j0;
#pragma unroll
    for (int u = 0; u < 8; u += 4) {
        *(float4*)&r[u] = *(const float4*)&ret[base + u];
        *(float4*)&g[u] = *(const float4*)&gat[base + u];
        *(float4*)&w[u] = *(const float4*)&Wl[base + u];
        *(float4*)&F[u] = *(const float4*)(Fi + u);
    }
    const size_t row0 = ((size_t)b * 2048 + (size_t)c * 128) * 3072;
    const float* bq = qkv + row0 + h * 64 + j0;
    const float* bk = bq + 1024;
    const float* bv = qkv + row0 + 2048 + h * 64 + i;
    u16* py = y + ((size_t)b * 2048 + (size_t)c * 128) * 1024 + h * 64 + i;

    float qA[8], qB[8], kA[8], kB[8], vA, vB;
#pragma unroll
    for (int u = 0; u < 8; u += 4) {
        *(float4*)&qA[u] = *(const float4*)(bq + u);
        *(float4*)&kA[u] = *(const float4*)(bk + u);
    }
    vA = *bv;

    unsigned offB = 3072, offA = 6144;
    for (int t = 0; t < 128; t += 2) {
#pragma unroll
        for (int u = 0; u < 8; u += 4) {
            *(float4*)&qB[u] = *(const float4*)(bq + offB + u);
            *(float4*)&kB[u] = *(const float4*)(bk + offB + u);
        }
        vB = *(bv + offB);
        offB += 6144;
        {
#pragma unroll
            for (int u = 0; u < 8; ++u) F[u] = r[u] * F[u] + (g[u] * kA[u]) * vA;
            float p0 = (w[0] + F[0]) * qA[0];
            float p1 = (w[1] + F[1]) * qA[1];
            p0 += (w[2] + F[2]) * qA[2];
            p1 += (w[3] + F[3]) * qA[3];
            p0 += (w[4] + F[4]) * qA[4];
            p1 += (w[5] + F[5]) * qA[5];
            p0 += (w[6] + F[6]) * qA[6];
            p1 += (w[7] + F[7]) * qA[7];
            float p = p0 + p1;
            p += __shfl_xor(p, 1);
            p += __shfl_xor(p, 2);
            p += __shfl_xor(p, 4);
            if (jq == 0) py[0] = f2b(p);
        }
#pragma unroll
        for (int u = 0; u < 8; u += 4) {
            *(float4*)&qA[u] = *(const float4*)(bq + offA + u);
            *(float4*)&kA[u] = *(const float4*)(bk + offA + u);
        }
        vA = *(bv + offA);
        offA += 6144;
        {
#pragma unroll
            for (int u = 0; u < 8; ++u) F[u] = r[u] * F[u] + (g[u] * kB[u]) * vB;
            float p0 = (w[0] + F[0]) * qB[0];
            float p1 = (w[1] + F[1]) * qB[1];
            p0 += (w[2] + F[2]) * qB[2];
            p1 += (w[3] + F[3]) * qB[3];
            p0 += (w[4] + F[4]) * qB[4];
            p1 += (w[5] + F[5]) * qB[5];
            p0 += (w[6] + F[6]) * qB[6];
            p1 += (w[7] + F[7]) * qB[7];
            float p = p0 + p1;
            p += __shfl_xor(p, 1);
            p += __shfl_xor(p, 2);
            p += __shfl_xor(p, 4);
            if (jq == 0) py[1024] = f2b(p);
        }
        py += 2048;
    }
}

extern "C" void kernel_launch(void* const* d_in, const int* in_sizes, int n_in,
                              void* d_out, int out_size, void* d_ws, size_t ws_size,
                              hipStream_t stream) {
    constexpr int Bz = 4, T = 2048, Dd = 1024, Hh = 16, Vv = 8192, Ll = 2;
    constexpr int Nn = Bz * T;   // 8192 tokens
    const int*   ids      = (const int*)d_in[0];
    const float* embed_W  = (const float*)d_in[2];
    const float* conv_w   = (const float*)d_in[3];
    const float* conv_b   = (const float*)d_in[4];
    const float* Wqkv     = (const float*)d_in[5];
    const float* Wo       = (const float*)d_in[6];
    const float* W_LTM    = (const float*)d_in[7];
    const float* V_T0     = (const float*)d_in[8];
    const float* V_gs     = (const float*)d_in[9];
    const float* beta_tau = (const float*)d_in[10];
    const float* beta_gm  = (const float*)d_in[11];
    const float* C_ch     = (const float*)d_in[12];
    const float* gammaP   = (const float*)d_in[13];
    const float* alphaP   = (const float*)d_in[14];
    const float* ICthr    = (const float*)d_in[15];
    const float* ln1_g    = (const float*)d_in[16];
    const float* ln1_b    = (const float*)d_in[17];
    const float* lnk_g    = (const float*)d_in[18];
    const float* lnk_b    = (const float*)d_in[19];
    const float* lnf_g    = (const float*)d_in[20];
    const float* lnf_b    = (const float*)d_in[21];
    const float* head_W   = (const float*)d_in[22];

    // workspace carve (~220 MB)
    float* x    = (float*)d_ws;                                  // fp32 N*D
    float* qkvF = x + (size_t)Nn * Dd;                           // fp32 N*3D
    float* ret  = qkvF + (size_t)Nn * 3 * Dd;                    // fp32 L*H*4096
    float* gat  = ret + (size_t)Ll * Hh * 4096;
    float* rp   = gat + (size_t)Ll * Hh * 4096;                  // fp32 L*H*4096 (r^128)
    float* hln  = rp + (size_t)Ll * Hh * 4096;                   // fp32 N*D
    u16*  yb    = (u16*)hln;                                     // bf16 N*D  (aliases hln 1st half)
    u16*  xf    = yb + (size_t)Nn * Dd;                          // bf16 N*D  (aliases hln 2nd half)
    float* Fin  = (float*)xf;                                    // fp32 B*H*16*4096
    u16*  hb    = (u16*)(hln + (size_t)Nn * Dd);                 // bf16 N*D
    float* Floc = (float*)hb;                                    // fp32 B*H*16*4096
    u16*  wq_b  = hb + (size_t)Nn * Dd;                          // bf16 L*3D*D
    u16*  wo_b  = wq_b + (size_t)Ll * 3 * Dd * Dd;               // bf16 L*D*D
    u16*  wh_b  = wo_b + (size_t)Ll * Dd * Dd;                   // bf16 V*D

    // weight conversions
    f2b_k<<<(Ll * 3 * Dd * Dd / 4 + 255) / 256, 256, 0, stream>>>(Wqkv, wq_b, Ll * 3 * Dd * Dd / 4);
    f2b_k<<<(Ll * Dd * Dd / 4 + 255) / 256, 256, 0, stream>>>(Wo, wo_b, Ll * Dd * Dd / 4);
    f2b_k<<<(Vv * Dd / 4 + 255) / 256, 256, 0, stream>>>(head_W, wh_b, Vv * Dd / 4);

    embed_k<<<Nn, 256, 0, stream>>>(ids, embed_W, x);
    physics_k<<<(Ll * Hh * 4096) / 256, 256, 0, stream>>>(W_LTM, V_T0, V_gs, beta_tau,
                                                          beta_gm, C_ch, gammaP, alphaP,
                                                          ICthr, ret, gat, rp);
    for (int l = 0; l < Ll; ++l) {
        const float* retl = ret + (size_t)l * Hh * 4096;
        const float* gatl = gat + (size_t)l * Hh * 4096;
        ln_rows<false><<<Nn, 256, 0, stream>>>(x, ln1_g + l * Dd, ln1_b + l * Dd, hln);
        conv_k<<<Nn, 256, 0, stream>>>(hln, conv_w + l * 3 * Dd, conv_b + l * Dd, hb);
        gemm256<0><<<(Nn / 256) * (3 * Dd / 256), 512, 0, stream>>>(
            hb, wq_b + (size_t)l * 3 * Dd * Dd, qkvF, 3 * Dd, Dd, 3 * Dd / 256);
        kln_k<<<Nn * Hh / 4, 256, 0, stream>>>(qkvF, lnk_g + l * 64, lnk_b + l * 64);
        scanA_k<<<Bz * Hh * 16, 256, 0, stream>>>(qkvF, retl, gatl, Floc);
        scanB_k<<<Bz * Hh * 4096 / 256, 256, 0, stream>>>(rp + (size_t)l * Hh * 4096, Floc, Fin);
        scanC_k<<<Bz * Hh * 16 * 2, 256, 0, stream>>>(qkvF, retl, gatl,
                                                      W_LTM + (size_t)l * Hh * 4096, Fin, yb);
        gemm_bt<1><<<dim3(Dd / 128, Nn / 128), 256, 0, stream>>>(
            yb, wo_b + (size_t)l * Dd * Dd, x, Dd, Dd);
    }
    ln_rows<true><<<Nn, 256, 0, stream>>>(x, lnf_g, lnf_b, xf);
    gemm256<0><<<(Nn / 256) * (Vv / 256), 512, 0, stream>>>(
        xf, wh_b, (float*)d_out, Vv, Dd, Vv / 256);
}

// Round 4
// 1372.391 us; speedup vs baseline: 1.0345x; 1.0332x over previous
//
#include <hip/hip_runtime.h>

typedef unsigned short u16;
typedef __attribute__((ext_vector_type(8))) short bf16x8;
typedef __attribute__((ext_vector_type(4))) float f32x4;

__device__ __forceinline__ u16 f2b(float f) {
    union { unsigned int i; float f; } x; x.f = f;
    unsigned int r = (x.i + 0x7fffu + ((x.i >> 16) & 1u)) >> 16;
    return (u16)r;
}

__device__ __forceinline__ void gload16(const u16* g, u16* l) {
    __builtin_amdgcn_global_load_lds(
        (const __attribute__((address_space(1))) void*)g,
        (__attribute__((address_space(3))) void*)l, 16, 0, 0);
}

// DPP butterfly add: v += v[lane ^ pattern]  (pure VALU, no DS)
template<int CTRL>
__device__ __forceinline__ float dpp_xadd(float v) {
    int s = __builtin_amdgcn_update_dpp(0, __builtin_bit_cast(int, v), CTRL, 0xf, 0xf, true);
    return v + __builtin_bit_cast(float, s);
}

// ---------------- fp32 -> bf16 weight conversion ----------------
__global__ __launch_bounds__(256) void f2b_k(const float* __restrict__ in,
                                             u16* __restrict__ out, int n4) {
    const int i = blockIdx.x * 256 + threadIdx.x;
    if (i < n4) {
        float4 v = ((const float4*)in)[i];
        ushort4 o = { f2b(v.x), f2b(v.y), f2b(v.z), f2b(v.w) };
        ((ushort4*)out)[i] = o;
    }
}

// ---------------- embedding gather ----------------
__global__ __launch_bounds__(256) void embed_k(const int* __restrict__ ids,
                                               const float* __restrict__ E,
                                               float* __restrict__ x) {
    const int n = blockIdx.x, t = threadIdx.x;
    const int id = ids[n];
    float4 e = ((const float4*)(E + (size_t)id * 1024))[t];
    ((float4*)(x + (size_t)n * 1024))[t] = e;
}

// ---------------- static physics ----------------
__global__ __launch_bounds__(256) void physics_k(
        const float* __restrict__ W_LTM, const float* __restrict__ V_T0,
        const float* __restrict__ V_gs, const float* __restrict__ beta_tau,
        const float* __restrict__ beta_gm, const float* __restrict__ C_ch,
        const float* __restrict__ gammaP, const float* __restrict__ alphaP,
        const float* __restrict__ ICthr, float* __restrict__ ret,
        float* __restrict__ gat, float* __restrict__ rp) {
    const int idx = blockIdx.x * 256 + threadIdx.x;   // < L*H*4096
    const int lh = idx >> 12;   // l*H + h
    const int l  = lh >> 4;     // H = 16
    const float W    = W_LTM[idx];
    const float veff = V_gs[lh] - V_T0[lh] + W;
    const float sp   = fmaxf(veff, 0.f) + log1pf(expf(-fabsf(veff)));  // softplus
    const float gch  = beta_tau[lh] * sp;
    const float G    = beta_gm[lh] * sp / (1.f + expf(-veff));
    const float sgn  = tanhf(alphaP[l] * (gch - ICthr[l]));
    const float e1   = gch / C_ch[lh];
    ret[idx] = expf(-e1);            // r = 1 - lam
    rp[idx]  = expf(-128.f * e1);    // r^128 (chunk decay)
    gat[idx] = gammaP[lh] * sgn * G;
}

// ---------------- LayerNorm over D=1024, one block per row ----------------
template<bool OUTB>
__global__ __launch_bounds__(256) void ln_rows(const float* __restrict__ X,
                                               const float* __restrict__ g,
                                               const float* __restrict__ bb,
                                               void* __restrict__ OUT) {
    const int n = blockIdx.x, t = threadIdx.x;
    const float4 xv = ((const float4*)(X + (size_t)n * 1024))[t];
    float s  = xv.x + xv.y + xv.z + xv.w;
    float s2 = xv.x * xv.x + xv.y * xv.y + xv.z * xv.z + xv.w * xv.w;
#pragma unroll
    for (int m = 32; m; m >>= 1) { s += __shfl_xor(s, m); s2 += __shfl_xor(s2, m); }
    __shared__ float sh[8];
    if ((t & 63) == 0) { sh[t >> 6] = s; sh[4 + (t >> 6)] = s2; }
    __syncthreads();
    s  = sh[0] + sh[1] + sh[2] + sh[3];
    s2 = sh[4] + sh[5] + sh[6] + sh[7];
    const float mean = s * (1.f / 1024.f);
    const float rstd = rsqrtf(s2 * (1.f / 1024.f) - mean * mean + 1e-5f);
    const int d0 = t * 4;
    const float4 gv = *(const float4*)&g[d0];
    const float4 bv = *(const float4*)&bb[d0];
    float o0 = (xv.x - mean) * rstd * gv.x + bv.x;
    float o1 = (xv.y - mean) * rstd * gv.y + bv.y;
    float o2 = (xv.z - mean) * rstd * gv.z + bv.z;
    float o3 = (xv.w - mean) * rstd * gv.w + bv.w;
    if (OUTB) {
        ushort4 o = { f2b(o0), f2b(o1), f2b(o2), f2b(o3) };
        ((ushort4*)((u16*)OUT + (size_t)n * 1024))[t] = o;
    } else {
        float4 o = { o0, o1, o2, o3 };
        ((float4*)((float*)OUT + (size_t)n * 1024))[t] = o;
    }
}

// ---------------- causal depthwise conv (k=3, left pad 2) + residual ----------------
__global__ __launch_bounds__(256) void conv_k(const float* __restrict__ hln,
                                              const float* __restrict__ w,
                                              const float* __restrict__ cb,
                                              u16* __restrict__ out) {
    const int n = blockIdx.x;
    const int tt = n & 2047;           // T = 2048
    const int d0 = threadIdx.x * 4;
    const float4 c = *(const float4*)&hln[(size_t)n * 1024 + d0];
    float4 m1 = { 0, 0, 0, 0 }, m2 = { 0, 0, 0, 0 };
    if (tt >= 1) m1 = *(const float4*)&hln[(size_t)(n - 1) * 1024 + d0];
    if (tt >= 2) m2 = *(const float4*)&hln[(size_t)(n - 2) * 1024 + d0];
    const float4 w0 = *(const float4*)&w[d0];
    const float4 w1 = *(const float4*)&w[1024 + d0];
    const float4 w2 = *(const float4*)&w[2048 + d0];
    const float4 cv = *(const float4*)&cb[d0];
    float o0 = c.x + m2.x * w0.x + m1.x * w1.x + c.x * w2.x + cv.x;
    float o1 = c.y + m2.y * w0.y + m1.y * w1.y + c.y * w2.y + cv.y;
    float o2 = c.z + m2.z * w0.z + m1.z * w1.z + c.z * w2.z + cv.z;
    float o3 = c.w + m2.w * w0.w + m1.w * w1.w + c.w * w2.w + cv.w;
    ushort4 o = { f2b(o0), f2b(o1), f2b(o2), f2b(o3) };
    *(ushort4*)&out[(size_t)n * 1024 + d0] = o;
}

// ---------------- k head-LN over dk=64, in-place on fp32 qkv ----------------
__global__ __launch_bounds__(256) void kln_k(float* __restrict__ qkv,
                                             const float* __restrict__ g,
                                             const float* __restrict__ bb) {
    const int row = blockIdx.x * 4 + (threadIdx.x >> 6);
    const int lane = threadIdx.x & 63;
    const int n = row >> 4, h = row & 15;        // H = 16
    float* p = qkv + (size_t)n * 3072 + 1024 + h * 64 + lane;
    const float x = *p;
    float s = x, s2 = x * x;
#pragma unroll
    for (int m = 32; m; m >>= 1) { s += __shfl_xor(s, m); s2 += __shfl_xor(s2, m); }
    const float mean = s * (1.f / 64.f);
    const float rstd = rsqrtf(s2 * (1.f / 64.f) - mean * mean + 1e-5f);
    *p = (x - mean) * rstd * g[lane] + bb[lane];
}

// ---------------- bf16 B^T GEMM, m97 recipe (kept for Wo: N=1024) ----------------
template<int MODE>
__global__ __launch_bounds__(256, 2) void gemm_bt(const u16* __restrict__ A,
                                                  const u16* __restrict__ Bm,
                                                  float* __restrict__ C,
                                                  int Nn, int K) {
    __shared__ u16 lA[128 * 32];
    __shared__ u16 lB[128 * 32];
    const int t = threadIdx.x;
    const int lane = t & 63, wave = t >> 6;
    const int wm = (wave >> 1) * 64, wn = (wave & 1) * 64;
    const int m0 = blockIdx.y * 128, n0 = blockIdx.x * 128;
    f32x4 acc[4][4] = {};
    const int sr = t >> 2, sc = (t & 3) * 8;
    const u16* Ap = A + (size_t)(m0 + sr) * K + sc;
    const u16* Bp = Bm + (size_t)(n0 + sr) * K + sc;
    u16* lAw = lA + t * 8;
    u16* lBw = lB + t * 8;
    const int fr = lane & 15, fk = (lane >> 4) * 8;
    for (int k0 = 0; k0 < K; k0 += 32) {
        __syncthreads();
        gload16(Ap, lAw);
        gload16(Ap + (size_t)64 * K, lAw + 2048);
        gload16(Bp, lBw);
        gload16(Bp + (size_t)64 * K, lBw + 2048);
        Ap += 32; Bp += 32;
        __syncthreads();
        bf16x8 af[4], bf[4];
#pragma unroll
        for (int i = 0; i < 4; ++i) af[i] = *(const bf16x8*)&lA[(wm + i * 16 + fr) * 32 + fk];
#pragma unroll
        for (int i = 0; i < 4; ++i) bf[i] = *(const bf16x8*)&lB[(wn + i * 16 + fr) * 32 + fk];
#pragma unroll
        for (int i = 0; i < 4; ++i)
#pragma unroll
            for (int j = 0; j < 4; ++j)
                acc[i][j] = __builtin_amdgcn_mfma_f32_16x16x32_bf16(af[i], bf[j], acc[i][j], 0, 0, 0);
    }
    const int col = lane & 15, rw = (lane >> 4) * 4;
#pragma unroll
    for (int i = 0; i < 4; ++i)
#pragma unroll
        for (int j = 0; j < 4; ++j)
#pragma unroll
            for (int r = 0; r < 4; ++r) {
                const int gm = m0 + wm + i * 16 + rw + r;
                const int gn = n0 + wn + j * 16 + col;
                if (MODE == 0) C[(size_t)gm * Nn + gn] = acc[i][j][r];
                else           C[(size_t)gm * Nn + gn] += acc[i][j][r];
            }
}

// ============ 256x256 8-phase bf16 B^T GEMM (T1+T2+T3+T4+T5) ============
template<int MODE>
__global__ __launch_bounds__(512, 2) void gemm256(const u16* __restrict__ A,
                                                  const u16* __restrict__ Bm,
                                                  float* __restrict__ C,
                                                  int Nn, int K, int ntiles) {
    __shared__ u16 lds[65536];   // [buf:2][A/B][kh:2][8192 u16]
    const int tid = threadIdx.x;
    const int lane = tid & 63, wave = tid >> 6;
    const int wm = wave >> 2, wn = wave & 3;
    // T1: XCD-aware swizzle (grid % 8 == 0 for all call sites)
    const int nwg = gridDim.x;
    const int cpx = nwg >> 3;
    const int bid0 = blockIdx.x;
    const int bid = (bid0 & 7) * cpx + (bid0 >> 3);
    const int m0 = (bid / ntiles) * 256, n0 = (bid % ntiles) * 256;

    // staging source (per thread); inverse-swizzled column
    const int sr = tid >> 2;                       // 0..127
    const int sc = (tid & 3) ^ ((tid >> 3) & 3);
    const u16* gA = A + (size_t)(m0 + sr) * K + sc * 8;
    const u16* gB = Bm + (size_t)(n0 + sr) * K + sc * 8;
    const size_t qstep = (size_t)128 * K;
    const int ldst = tid * 8;                      // staging dest (u16), +4096 for rows 128..255

    // frag read offsets (u16): chunk = row*4 + (g ^ ((row>>1)&3)), addr = chunk*8
    const int laneRow = lane & 15, g4 = lane >> 4;
    const int swz = g4 ^ ((laneRow >> 1) & 3);
    const int pA = ((wm * 128 + laneRow) * 4 + swz) * 8;   // + f*512
    const int pB = ((wn * 64 + laneRow) * 4 + swz) * 8;    // + nf*512

    f32x4 acc[8][4] = {};
    const int NT = K >> 6;

    // ---- prologue: stage tile 0 (A-K0, B-K0, A-K1, B-K1) ----
    {
        u16* d = (u16*)lds;
        gload16(gA,              d + ldst);
        gload16(gA + qstep,      d + 4096 + ldst);
        gload16(gB,              d + 16384 + ldst);
        gload16(gB + qstep,      d + 16384 + 4096 + ldst);
        gload16(gA + 32,         d + 8192 + ldst);
        gload16(gA + 32 + qstep, d + 8192 + 4096 + ldst);
        gload16(gB + 32,         d + 24576 + ldst);
        gload16(gB + 32 + qstep, d + 24576 + 4096 + ldst);
    }
    asm volatile("s_waitcnt vmcnt(4)" ::: "memory");
    __builtin_amdgcn_s_barrier();

    for (int t = 0; t < NT; ++t) {
        const u16* lb = lds + (t & 1) * 32768;
        u16* sb = (u16*)lds + ((t + 1) & 1) * 32768;
        const bool st = (t + 1 < NT);
        const int ko = (t + 1) * 64;
        bf16x8 a[8], b0, b1, b2, b3;

        // ---------- phase 1: A-K0 frags + B-K0 lo; stage A-K0 of t+1 ----------
#pragma unroll
        for (int f = 0; f < 8; ++f) a[f] = *(const bf16x8*)(lb + pA + f * 512);
        b0 = *(const bf16x8*)(lb + 16384 + pB);
        b1 = *(const bf16x8*)(lb + 16384 + pB + 512);
        if (st) { gload16(gA + ko, sb + ldst); gload16(gA + ko + qstep, sb + 4096 + ldst); }
        __builtin_amdgcn_s_barrier();
        asm volatile("s_waitcnt lgkmcnt(0)" ::: "memory");
        __builtin_amdgcn_sched_barrier(0);
        __builtin_amdgcn_s_setprio(1);
#pragma unroll
        for (int m = 0; m < 8; ++m) {
            acc[m][0] = __builtin_amdgcn_mfma_f32_16x16x32_bf16(a[m], b0, acc[m][0], 0, 0, 0);
            acc[m][1] = __builtin_amdgcn_mfma_f32_16x16x32_bf16(a[m], b1, acc[m][1], 0, 0, 0);
        }
        __builtin_amdgcn_s_setprio(0);
        __builtin_amdgcn_s_barrier();

        // ---------- phase 2: B-K0 hi; stage B-K0 of t+1; vmcnt(4) ----------
        b2 = *(const bf16x8*)(lb + 16384 + pB + 1024);
        b3 = *(const bf16x8*)(lb + 16384 + pB + 1536);
        if (st) { gload16(gB + ko, sb + 16384 + ldst); gload16(gB + ko + qstep, sb + 16384 + 4096 + ldst); }
        if (st) asm volatile("s_waitcnt vmcnt(4)" ::: "memory");
        else    asm volatile("s_waitcnt vmcnt(0)" ::: "memory");
        __builtin_amdgcn_s_barrier();
        asm volatile("s_waitcnt lgkmcnt(0)" ::: "memory");
        __builtin_amdgcn_sched_barrier(0);
        __builtin_amdgcn_s_setprio(1);
#pragma unroll
        for (int m = 0; m < 8; ++m) {
            acc[m][2] = __builtin_amdgcn_mfma_f32_16x16x32_bf16(a[m], b2, acc[m][2], 0, 0, 0);
            acc[m][3] = __builtin_amdgcn_mfma_f32_16x16x32_bf16(a[m], b3, acc[m][3], 0, 0, 0);
        }
        __builtin_amdgcn_s_setprio(0);
        __builtin_amdgcn_s_barrier();

        // ---------- phase 3: A-K1 frags + B-K1 lo; stage A-K1 of t+1 ----------
#pragma unroll
        for (int f = 0; f < 8; ++f) a[f] = *(const bf16x8*)(lb + 8192 + pA + f * 512);
        b0 = *(const bf16x8*)(lb + 24576 + pB);
        b1 = *(const bf16x8*)(lb + 24576 + pB + 512);
        if (st) { gload16(gA + ko + 32, sb + 8192 + ldst); gload16(gA + ko + 32 + qstep, sb + 8192 + 4096 + ldst); }
        __builtin_amdgcn_s_barrier();
        asm volatile("s_waitcnt lgkmcnt(0)" ::: "memory");
        __builtin_amdgcn_sched_barrier(0);
        __builtin_amdgcn_s_setprio(1);
#pragma unroll
        for (int m = 0; m < 8; ++m) {
            acc[m][0] = __builtin_amdgcn_mfma_f32_16x16x32_bf16(a[m], b0, acc[m][0], 0, 0, 0);
            acc[m][1] = __builtin_amdgcn_mfma_f32_16x16x32_bf16(a[m], b1, acc[m][1], 0, 0, 0);
        }
        __builtin_amdgcn_s_setprio(0);
        __builtin_amdgcn_s_barrier();

        // ---------- phase 4: B-K1 hi; stage B-K1 of t+1; vmcnt(4) ----------
        b2 = *(const bf16x8*)(lb + 24576 + pB + 1024);
        b3 = *(const bf16x8*)(lb + 24576 + pB + 1536);
        if (st) { gload16(gB + ko + 32, sb + 24576 + ldst); gload16(gB + ko + 32 + qstep, sb + 24576 + 4096 + ldst); }
        if (st) asm volatile("s_waitcnt vmcnt(4)" ::: "memory");
        else    asm volatile("s_waitcnt vmcnt(0)" ::: "memory");
        __builtin_amdgcn_s_barrier();
        asm volatile("s_waitcnt lgkmcnt(0)" ::: "memory");
        __builtin_amdgcn_sched_barrier(0);
        __builtin_amdgcn_s_setprio(1);
#pragma unroll
        for (int m = 0; m < 8; ++m) {
            acc[m][2] = __builtin_amdgcn_mfma_f32_16x16x32_bf16(a[m], b2, acc[m][2], 0, 0, 0);
            acc[m][3] = __builtin_amdgcn_mfma_f32_16x16x32_bf16(a[m], b3, acc[m][3], 0, 0, 0);
        }
        __builtin_amdgcn_s_setprio(0);
        __builtin_amdgcn_s_barrier();
    }

    // ---- epilogue: C write ----
    const int col = lane & 15, rw4 = (lane >> 4) * 4;
    const int gm0 = m0 + wm * 128, gn0 = n0 + wn * 64;
#pragma unroll
    for (int m = 0; m < 8; ++m)
#pragma unroll
        for (int n = 0; n < 4; ++n) {
            float* cp = C + (size_t)(gm0 + m * 16 + rw4) * Nn + gn0 + n * 16 + col;
#pragma unroll
            for (int r = 0; r < 4; ++r) {
                if (MODE == 0) cp[(size_t)r * Nn] = acc[m][n][r];
                else           cp[(size_t)r * Nn] += acc[m][n][r];
            }
        }
}

// ============== chunked linear scan: F_t = r*F_{t-1} + g*(v_t k_t^T) ==============
// 16 chunks of 128 steps. Prefetch double-buffers are PINNED with
// sched_barrier(0): without it the compiler sinks the loads to their uses
// (observed: VGPR_Count 40 < the 48 the buffers need) and the pipeline
// degenerates to load-use stalls.

// Pass A: chunk-local final state (zero init), k/v only.
__global__ __launch_bounds__(256, 4) void scanA_k(const float* __restrict__ qkv,
                                                  const float* __restrict__ ret,
                                                  const float* __restrict__ gat,
                                                  float* __restrict__ Floc) {
    const int bid = blockIdx.x;
    const int c = bid & 15, h = (bid >> 4) & 15, b = bid >> 8;
    const int i = threadIdx.x >> 2;
    const int j0 = (threadIdx.x & 3) * 16;
    const int base = (h * 64 + i) * 64 + j0;
    float r[16], g[16], F[16];
#pragma unroll
    for (int u = 0; u < 16; u += 4) {
        *(float4*)&r[u] = *(const float4*)&ret[base + u];
        *(float4*)&g[u] = *(const float4*)&gat[base + u];
    }
#pragma unroll
    for (int u = 0; u < 16; ++u) F[u] = 0.f;

    const size_t row0 = ((size_t)b * 2048 + (size_t)c * 128) * 3072;
    const float* bk = qkv + row0 + 1024 + h * 64 + j0;
    const float* bv = qkv + row0 + 2048 + h * 64 + i;

    float kA[16], kB[16], vA, vB;
#pragma unroll
    for (int u = 0; u < 16; u += 4) *(float4*)&kA[u] = *(const float4*)(bk + u);
    vA = *bv;

    unsigned offB = 3072, offA = 6144;
    for (int t = 0; t < 128; t += 2) {
        // prefetch t+1 -> B  (pinned before compute)
#pragma unroll
        for (int u = 0; u < 16; u += 4) *(float4*)&kB[u] = *(const float4*)(bk + offB + u);
        vB = *(bv + offB);
        offB += 6144;
        __builtin_amdgcn_sched_barrier(0);
        // compute t (A)
#pragma unroll
        for (int u = 0; u < 16; ++u) F[u] = r[u] * F[u] + (g[u] * kA[u]) * vA;
        // prefetch t+2 -> A  (pinned)
#pragma unroll
        for (int u = 0; u < 16; u += 4) *(float4*)&kA[u] = *(const float4*)(bk + offA + u);
        vA = *(bv + offA);
        offA += 6144;
        __builtin_amdgcn_sched_barrier(0);
        // compute t+1 (B)
#pragma unroll
        for (int u = 0; u < 16; ++u) F[u] = r[u] * F[u] + (g[u] * kB[u]) * vB;
    }
    float* Fo = Floc + ((size_t)((b * 16 + h) * 16 + c)) * 4096 + i * 64 + j0;
#pragma unroll
    for (int u = 0; u < 16; u += 4) *(float4*)&Fo[u] = *(const float4*)&F[u];
}

// Pass B: prefix across chunks.
__global__ __launch_bounds__(256) void scanB_k(const float* __restrict__ rp,
                                               const float* __restrict__ Floc,
                                               float* __restrict__ Fin) {
    const int idx = blockIdx.x * 256 + threadIdx.x;   // < B*H*4096
    const int e = idx & 4095;
    const int bh = idx >> 12;
    const int h = bh & 15;
    const float rpv = rp[h * 4096 + e];
    float F = 0.f;
#pragma unroll
    for (int c = 0; c < 16; ++c) {
        const size_t o = ((size_t)bh * 16 + c) * 4096 + e;
        Fin[o] = F;
        F = rpv * F + Floc[o];
    }
}

// Pass C: outputs, seeded with Fin. DPP reduction over jq (3 VALU adds,
// same tree order as the old shfl_xor 1/2/4 -> bit-identical).
__global__ __launch_bounds__(256, 4) void scanC_k(const float* __restrict__ qkv,
                                                  const float* __restrict__ ret,
                                                  const float* __restrict__ gat,
                                                  const float* __restrict__ Wl,
                                                  const float* __restrict__ Fin,
                                                  u16* __restrict__ y) {
    const int bid = blockIdx.x;
    const int ig = bid & 1, c = (bid >> 1) & 15, h = (bid >> 5) & 15, b = bid >> 9;
    const int il = threadIdx.x >> 3;
    const int jq = threadIdx.x & 7;
    const int i = ig * 32 + il, j0 = jq * 8;
    const int base = (h * 64 + i) * 64 + j0;
    float r[8], g[8], w[8], F[8];
    const float* Fi = Fin + ((size_t)((b * 16 + h) * 16 + c)) * 4096 + i * 64 + j0;
#pragma unroll
    for (int u = 0; u < 8; u += 4) {
        *(float4*)&r[u] = *(const float4*)&ret[base + u];
        *(float4*)&g[u] = *(const float4*)&gat[base + u];
        *(float4*)&w[u] = *(const float4*)&Wl[base + u];
        *(float4*)&F[u] = *(const float4*)(Fi + u);
    }
    const size_t row0 = ((size_t)b * 2048 + (size_t)c * 128) * 3072;
    const float* bq = qkv + row0 + h * 64 + j0;
    const float* bk = bq + 1024;
    const float* bv = qkv + row0 + 2048 + h * 64 + i;
    u16* py = y + ((size_t)b * 2048 + (size_t)c * 128) * 1024 + h * 64 + i;

    float qA[8], qB[8], kA[8], kB[8], vA, vB;
#pragma unroll
    for (int u = 0; u < 8; u += 4) {
        *(float4*)&qA[u] = *(const float4*)(bq + u);
        *(float4*)&kA[u] = *(const float4*)(bk + u);
    }
    vA = *bv;

    unsigned offB = 3072, offA = 6144;
    for (int t = 0; t < 128; t += 2) {
        // prefetch t+1 -> B (pinned before compute)
#pragma unroll
        for (int u = 0; u < 8; u += 4) {
            *(float4*)&qB[u] = *(const float4*)(bq + offB + u);
            *(float4*)&kB[u] = *(const float4*)(bk + offB + u);
        }
        vB = *(bv + offB);
        offB += 6144;
        __builtin_amdgcn_sched_barrier(0);
        // compute t (A)
        {
#pragma unroll
            for (int u = 0; u < 8; ++u) F[u] = r[u] * F[u] + (g[u] * kA[u]) * vA;
            float p0 = (w[0] + F[0]) * qA[0];
            float p1 = (w[1] + F[1]) * qA[1];
            p0 += (w[2] + F[2]) * qA[2];
            p1 += (w[3] + F[3]) * qA[3];
            p0 += (w[4] + F[4]) * qA[4];
            p1 += (w[5] + F[5]) * qA[5];
            p0 += (w[6] + F[6]) * qA[6];
            p1 += (w[7] + F[7]) * qA[7];
            float p = p0 + p1;
            p = dpp_xadd<0xB1>(p);    // ^1  quad_perm[1,0,3,2]
            p = dpp_xadd<0x4E>(p);    // ^2  quad_perm[2,3,0,1]
            p = dpp_xadd<0x141>(p);   // ^7 == ^4 (quads already uniform)
            if (jq == 0) py[0] = f2b(p);
        }
        // prefetch t+2 -> A (pinned)
#pragma unroll
        for (int u = 0; u < 8; u += 4) {
            *(float4*)&qA[u] = *(const float4*)(bq + offA + u);
            *(float4*)&kA[u] = *(const float4*)(bk + offA + u);
        }
        vA = *(bv + offA);
        offA += 6144;
        __builtin_amdgcn_sched_barrier(0);
        // compute t+1 (B)
        {
#pragma unroll
            for (int u = 0; u < 8; ++u) F[u] = r[u] * F[u] + (g[u] * kB[u]) * vB;
            float p0 = (w[0] + F[0]) * qB[0];
            float p1 = (w[1] + F[1]) * qB[1];
            p0 += (w[2] + F[2]) * qB[2];
            p1 += (w[3] + F[3]) * qB[3];
            p0 += (w[4] + F[4]) * qB[4];
            p1 += (w[5] + F[5]) * qB[5];
            p0 += (w[6] + F[6]) * qB[6];
            p1 += (w[7] + F[7]) * qB[7];
            float p = p0 + p1;
            p = dpp_xadd<0xB1>(p);
            p = dpp_xadd<0x4E>(p);
            p = dpp_xadd<0x141>(p);
            if (jq == 0) py[1024] = f2b(p);
        }
        py += 2048;
    }
}

extern "C" void kernel_launch(void* const* d_in, const int* in_sizes, int n_in,
                              void* d_out, int out_size, void* d_ws, size_t ws_size,
                              hipStream_t stream) {
    constexpr int Bz = 4, T = 2048, Dd = 1024, Hh = 16, Vv = 8192, Ll = 2;
    constexpr int Nn = Bz * T;   // 8192 tokens
    const int*   ids      = (const int*)d_in[0];
    const float* embed_W  = (const float*)d_in[2];
    const float* conv_w   = (const float*)d_in[3];
    const float* conv_b   = (const float*)d_in[4];
    const float* Wqkv     = (const float*)d_in[5];
    const float* Wo       = (const float*)d_in[6];
    const float* W_LTM    = (const float*)d_in[7];
    const float* V_T0     = (const float*)d_in[8];
    const float* V_gs     = (const float*)d_in[9];
    const float* beta_tau = (const float*)d_in[10];
    const float* beta_gm  = (const float*)d_in[11];
    const float* C_ch     = (const float*)d_in[12];
    const float* gammaP   = (const float*)d_in[13];
    const float* alphaP   = (const float*)d_in[14];
    const float* ICthr    = (const float*)d_in[15];
    const float* ln1_g    = (const float*)d_in[16];
    const float* ln1_b    = (const float*)d_in[17];
    const float* lnk_g    = (const float*)d_in[18];
    const float* lnk_b    = (const float*)d_in[19];
    const float* lnf_g    = (const float*)d_in[20];
    const float* lnf_b    = (const float*)d_in[21];
    const float* head_W   = (const float*)d_in[22];

    // workspace carve (~220 MB)
    float* x    = (float*)d_ws;                                  // fp32 N*D
    float* qkvF = x + (size_t)Nn * Dd;                           // fp32 N*3D
    float* ret  = qkvF + (size_t)Nn * 3 * Dd;                    // fp32 L*H*4096
    float* gat  = ret + (size_t)Ll * Hh * 4096;
    float* rp   = gat + (size_t)Ll * Hh * 4096;                  // fp32 L*H*4096 (r^128)
    float* hln  = rp + (size_t)Ll * Hh * 4096;                   // fp32 N*D
    u16*  yb    = (u16*)hln;                                     // bf16 N*D  (aliases hln 1st half)
    u16*  xf    = yb + (size_t)Nn * Dd;                          // bf16 N*D  (aliases hln 2nd half)
    float* Fin  = (float*)xf;                                    // fp32 B*H*16*4096
    u16*  hb    = (u16*)(hln + (size_t)Nn * Dd);                 // bf16 N*D
    float* Floc = (float*)hb;                                    // fp32 B*H*16*4096
    u16*  wq_b  = hb + (size_t)Nn * Dd;                          // bf16 L*3D*D
    u16*  wo_b  = wq_b + (size_t)Ll * 3 * Dd * Dd;               // bf16 L*D*D
    u16*  wh_b  = wo_b + (size_t)Ll * Dd * Dd;                   // bf16 V*D

    // weight conversions
    f2b_k<<<(Ll * 3 * Dd * Dd / 4 + 255) / 256, 256, 0, stream>>>(Wqkv, wq_b, Ll * 3 * Dd * Dd / 4);
    f2b_k<<<(Ll * Dd * Dd / 4 + 255) / 256, 256, 0, stream>>>(Wo, wo_b, Ll * Dd * Dd / 4);
    f2b_k<<<(Vv * Dd / 4 + 255) / 256, 256, 0, stream>>>(head_W, wh_b, Vv * Dd / 4);

    embed_k<<<Nn, 256, 0, stream>>>(ids, embed_W, x);
    physics_k<<<(Ll * Hh * 4096) / 256, 256, 0, stream>>>(W_LTM, V_T0, V_gs, beta_tau,
                                                          beta_gm, C_ch, gammaP, alphaP,
                                                          ICthr, ret, gat, rp);
    for (int l = 0; l < Ll; ++l) {
        const float* retl = ret + (size_t)l * Hh * 4096;
        const float* gatl = gat + (size_t)l * Hh * 4096;
        ln_rows<false><<<Nn, 256, 0, stream>>>(x, ln1_g + l * Dd, ln1_b + l * Dd, hln);
        conv_k<<<Nn, 256, 0, stream>>>(hln, conv_w + l * 3 * Dd, conv_b + l * Dd, hb);
        gemm256<0><<<(Nn / 256) * (3 * Dd / 256), 512, 0, stream>>>(
            hb, wq_b + (size_t)l * 3 * Dd * Dd, qkvF, 3 * Dd, Dd, 3 * Dd / 256);
        kln_k<<<Nn * Hh / 4, 256, 0, stream>>>(qkvF, lnk_g + l * 64, lnk_b + l * 64);
        scanA_k<<<Bz * Hh * 16, 256, 0, stream>>>(qkvF, retl, gatl, Floc);
        scanB_k<<<Bz * Hh * 4096 / 256, 256, 0, stream>>>(rp + (size_t)l * Hh * 4096, Floc, Fin);
        scanC_k<<<Bz * Hh * 16 * 2, 256, 0, stream>>>(qkvF, retl, gatl,
                                                      W_LTM + (size_t)l * Hh * 4096, Fin, yb);
        gemm_bt<1><<<dim3(Dd / 128, Nn / 128), 256, 0, stream>>>(
            yb, wo_b + (size_t)l * Dd * Dd, x, Dd, Dd);
    }
    ln_rows<true><<<Nn, 256, 0, stream>>>(x, lnf_g, lnf_b, xf);
    gemm256<0><<<(Nn / 256) * (Vv / 256), 512, 0, stream>>>(
        xf, wh_b, (float*)d_out, Vv, Dd, Vv / 256);
}